// Round 1
// baseline (131.051 us; speedup 1.0000x reference)
//
#include <hip/hip_runtime.h>
#include <hip/hip_bf16.h>
#include <math.h>

// SO3 convolution, lmax=2: S=9 spherical-harmonic channels, F=128 basis.
// Restructured contraction: per edge build M[9][9] = sum_k cg_val[k]*Y[i2[k]]
// at slot (i3[k], i1[k]); then y[e,s3,f] = Wl[l(s3)][f] * sum_s1 M[s3][s1]*xj[s1][f].
// One block (128 threads = 2 waves) per edge; f = threadIdx.x.

#define S9 9
#define NF 128
#define NRAD 20

__global__ __launch_bounds__(128) void so3_edge_kernel(
    const float* __restrict__ x,        // [A, 9, 128]
    const float* __restrict__ radial,   // [E, 20]
    const float* __restrict__ dir,      // [E, 3]
    const float* __restrict__ cutoff,   // [E]
    const float* __restrict__ Wf,       // [20, 384]  (384 = l*128 + f)
    const float* __restrict__ bf,       // [384]
    const float* __restrict__ cg_vals,  // [ncg]
    const int* __restrict__ idx_i,      // [E]
    const int* __restrict__ idx_j,      // [E]
    const int* __restrict__ cg_i1,      // [ncg]
    const int* __restrict__ cg_i2,      // [ncg]
    const int* __restrict__ cg_i3,      // [ncg]
    int ncg,
    float* __restrict__ out)            // [A, 9, 128]
{
    const int e = blockIdx.x;
    const int f = threadIdx.x;

    __shared__ float M[81];     // M[s3*9 + s1]
    __shared__ float Ysh[9];

    // ---- direction + spherical harmonics (all threads compute d; lane 0 writes Y) ----
    float dx = dir[e * 3 + 0];
    float dy = dir[e * 3 + 1];
    float dz = dir[e * 3 + 2];
    float inv = rsqrtf(dx * dx + dy * dy + dz * dz);
    dx *= inv; dy *= inv; dz *= inv;

    if (f < 81) M[f] = 0.0f;
    if (f == 0) {
        const float s3c  = 1.7320508075688772f;   // sqrt(3)
        const float s5c  = 2.2360679774997896f;   // sqrt(5)
        const float s15c = 3.8729833462074170f;   // sqrt(15)
        Ysh[0] = 1.0f;
        Ysh[1] = s3c * dy;
        Ysh[2] = s3c * dz;
        Ysh[3] = s3c * dx;
        Ysh[4] = s15c * dx * dy;
        Ysh[5] = s15c * dy * dz;
        Ysh[6] = 0.5f * s5c * (3.0f * dz * dz - 1.0f);
        Ysh[7] = s15c * dx * dz;
        Ysh[8] = 0.5f * s15c * (dx * dx - dy * dy);
    }
    __syncthreads();

    // ---- build M[9][9] from sparse CG entries (LDS atomics; ncg ~ O(150)) ----
    for (int k = f; k < ncg; k += NF) {
        int i1 = cg_i1[k];
        int i2 = cg_i2[k];
        int i3 = cg_i3[k];
        atomicAdd(&M[i3 * S9 + i1], cg_vals[k] * Ysh[i2]);
    }
    __syncthreads();

    // ---- per-l radial filter: Wl[l][f] = (radial[e] . Wf[:, l*128+f] + bf) * cutoff ----
    float rad[NRAD];
    #pragma unroll
    for (int r = 0; r < NRAD; ++r) rad[r] = radial[e * NRAD + r];
    const float cut = cutoff[e];

    float wl[3];
    #pragma unroll
    for (int l = 0; l < 3; ++l) {
        float a = bf[l * NF + f];
        #pragma unroll
        for (int r = 0; r < NRAD; ++r)
            a = fmaf(rad[r], Wf[r * 384 + l * NF + f], a);
        wl[l] = a * cut;
    }

    // ---- gather neighbor features (coalesced across f) ----
    const int j = idx_j[e];
    const float* xjp = x + (size_t)j * (S9 * NF) + f;
    float xj[S9];
    #pragma unroll
    for (int s = 0; s < S9; ++s) xj[s] = xjp[s * NF];

    // ---- dense 9x9 contraction, then scale by per-l filter, scatter-add ----
    const int i = idx_i[e];
    float* outp = out + (size_t)i * (S9 * NF) + f;

    #pragma unroll
    for (int s3 = 0; s3 < S9; ++s3) {
        float a = 0.0f;
        #pragma unroll
        for (int s1 = 0; s1 < S9; ++s1)
            a = fmaf(M[s3 * S9 + s1], xj[s1], a);
        // l of output combined index: s3=0 -> l0; 1..3 -> l1; 4..8 -> l2
        const int l3 = (s3 == 0) ? 0 : ((s3 < 4) ? 1 : 2);
        atomicAdd(&outp[s3 * NF], a * wl[l3]);
    }
}

extern "C" void kernel_launch(void* const* d_in, const int* in_sizes, int n_in,
                              void* d_out, int out_size, void* d_ws, size_t ws_size,
                              hipStream_t stream) {
    const float* x       = (const float*)d_in[0];
    const float* radial  = (const float*)d_in[1];
    const float* dir     = (const float*)d_in[2];
    const float* cutoff  = (const float*)d_in[3];
    const float* Wf      = (const float*)d_in[4];
    const float* bf      = (const float*)d_in[5];
    const float* cg_vals = (const float*)d_in[6];
    const int*   idx_i   = (const int*)d_in[7];
    const int*   idx_j   = (const int*)d_in[8];
    const int*   cg_i1   = (const int*)d_in[9];
    const int*   cg_i2   = (const int*)d_in[10];
    const int*   cg_i3   = (const int*)d_in[11];
    // d_in[12] = w_idx: unused — w_idx[k] == l(cg_idx_out[k]), folded into the kernel.

    const int E   = in_sizes[7];
    const int ncg = in_sizes[6];

    float* out = (float*)d_out;

    // d_out is poisoned with 0xAA before every timed launch — zero it first.
    hipMemsetAsync(out, 0, (size_t)out_size * sizeof(float), stream);

    so3_edge_kernel<<<E, 128, 0, stream>>>(
        x, radial, dir, cutoff, Wf, bf, cg_vals,
        idx_i, idx_j, cg_i1, cg_i2, cg_i3, ncg, out);
}